// Round 1
// baseline (860.677 us; speedup 1.0000x reference)
//
#include <hip/hip_runtime.h>
#include <hip/hip_bf16.h>
#include <cstdint>
#include <cstddef>

typedef __attribute__((ext_vector_type(8))) short short8;
typedef __attribute__((ext_vector_type(4))) float floatx4;

// ---------------- constants ----------------
// V=1024 C=8 T=256 BP=4 K=512 E=128 D=128 NB=24 NH=4 HD=32 FF=512 R=8 B=32

__device__ __forceinline__ ushort f2bf(float f) {
    union { float f; unsigned int u; } x; x.f = f;
    unsigned int r = (x.u + 0x7fffu + ((x.u >> 16) & 1u)) >> 16;
    return (ushort)r;
}

// ---------------- prep kernels ----------------
__global__ __launch_bounds__(256) void prep_misc(
    const float* __restrict__ emb, const float* __restrict__ w2,
    const float* __restrict__ cbi, const float* __restrict__ cbv,
    ushort* __restrict__ ebf, ushort* __restrict__ w2bf,
    float* __restrict__ cbiT, float* __restrict__ cbvT, float* __restrict__ accum)
{
    int idx = blockIdx.x * 256 + threadIdx.x;
    if (idx < 2) accum[idx] = 0.f;
    if (idx < 131072) {
        ebf[idx] = f2bf(emb[idx]);
    } else if (idx < 262144) {
        int j = idx - 131072;
        w2bf[j] = f2bf(w2[j]);
    } else if (idx < 327680) {
        int j = idx - 262144;            // j = k*128 + d
        cbiT[(j & 127) * 512 + (j >> 7)] = cbi[j];
    } else if (idx < 393216) {
        int j = idx - 327680;
        cbvT[(j & 127) * 512 + (j >> 7)] = cbv[j];
    }
}

// w1bf[kw][c][co][e]  <-  conv1_w[co][c*128+e][kw]
__global__ __launch_bounds__(256) void prep_w1(
    const float* __restrict__ w1, ushort* __restrict__ w1bf)
{
    int idx = blockIdx.x * 256 + threadIdx.x;   // < 1572864
    int e  = idx & 127;
    int co = (idx >> 7) & 511;
    int cc = (idx >> 16) & 7;
    int kw = idx >> 19;
    w1bf[idx] = f2bf(w1[(co * 1024 + cc * 128 + e) * 3 + kw]);
}

// ---------------- conv1: implicit GEMM, bf16 MFMA ----------------
// grid 1536: bx>>2 = m-tile (set,b,t0), bx&3 = n-tile (co block of 128)
__global__ __launch_bounds__(256) void conv1_mfma(
    const int* __restrict__ tp, const int* __restrict__ tcu, const int* __restrict__ tn,
    const ushort* __restrict__ ebf, const ushort* __restrict__ w1bf,
    const float* __restrict__ b1, ushort* __restrict__ y1)
{
    constexpr int LDA = 136;  // 128 + 8 bf16 pad (keeps 16B align, 2-way banks = free)
    __shared__ ushort As[64 * LDA];
    __shared__ ushort Bs[128 * LDA];
    const int tid = threadIdx.x;
    const int bx = blockIdx.x;
    const int nb = bx & 3, mb = bx >> 2;
    const int set = mb >> 7, bb = (mb >> 2) & 31, t0 = (mb & 3) << 6;
    const int n0 = nb << 7;
    const int* tok = (set == 0) ? tp : ((set == 1) ? tcu : tn);
    const int w = tid >> 6, lane = tid & 63;
    const int rA = lane & 15, q4 = lane >> 4;

    floatx4 acc[4][2];
    for (int mi = 0; mi < 4; ++mi)
        for (int ni = 0; ni < 2; ++ni)
            acc[mi][ni] = (floatx4)(0.0f);

    const int ch = tid & 15;
    for (int kc = 0; kc < 24; ++kc) {
        const int kw = kc >> 3, cc = kc & 7;
        // stage A: 64 rows (t) x 128 (e), gathered token embeddings
        for (int i = 0; i < 4; ++i) {
            const int row = i * 16 + (tid >> 4);
            const int t = t0 + row + kw - 1;
            uint4 val = make_uint4(0u, 0u, 0u, 0u);
            if (t >= 0 && t < 256) {
                const int token = tok[bb * 2048 + t * 8 + cc];
                val = *(const uint4*)(ebf + token * 128 + ch * 8);
            }
            *(uint4*)(As + row * LDA + ch * 8) = val;
        }
        // stage Bt: 128 rows (co) x 128 (e)
        const ushort* wsrc = w1bf + ((size_t)((kw * 8 + cc) * 512 + n0)) * 128;
        for (int i = 0; i < 8; ++i) {
            const int row = i * 16 + (tid >> 4);
            *(uint4*)(Bs + row * LDA + ch * 8) = *(const uint4*)(wsrc + row * 128 + ch * 8);
        }
        __syncthreads();
        for (int ks = 0; ks < 4; ++ks) {
            const int k0 = ks * 32 + q4 * 8;
            short8 a[4], bf[2];
            for (int mi = 0; mi < 4; ++mi)
                a[mi] = *(const short8*)(As + (mi * 16 + rA) * LDA + k0);
            for (int ni = 0; ni < 2; ++ni)
                bf[ni] = *(const short8*)(Bs + ((w * 2 + ni) * 16 + rA) * LDA + k0);
            for (int mi = 0; mi < 4; ++mi)
                for (int ni = 0; ni < 2; ++ni)
                    acc[mi][ni] = __builtin_amdgcn_mfma_f32_16x16x32_bf16(
                        a[mi], bf[ni], acc[mi][ni], 0, 0, 0);
        }
        __syncthreads();
    }
    // epilogue: bias + relu -> y1 bf16, layout [set][b][t][co]
    for (int ni = 0; ni < 2; ++ni) {
        const int co = n0 + (w * 2 + ni) * 16 + rA;
        const float bias = b1[co];
        for (int mi = 0; mi < 4; ++mi) {
            for (int r = 0; r < 4; ++r) {
                const int t = t0 + mi * 16 + q4 * 4 + r;
                float v = acc[mi][ni][r] + bias;
                v = v > 0.f ? v : 0.f;
                y1[((size_t)(set * 32 + bb) * 256 + t) * 512 + co] = f2bf(v);
            }
        }
    }
}

// ---------------- conv2 + avgpool(64): bf16 MFMA ----------------
// grid 768: bx>>1 = m-tile (set,b,p), bx&1 = n-tile (co2 block of 128)
__global__ __launch_bounds__(256) void conv2_mfma(
    const ushort* __restrict__ y1, const ushort* __restrict__ w2bf,
    const float* __restrict__ b2, float* __restrict__ y2)
{
    constexpr int LDA = 136;
    __shared__ ushort As[64 * LDA];
    __shared__ ushort Bs[128 * LDA];
    __shared__ float pool[128];
    const int tid = threadIdx.x;
    const int bx = blockIdx.x;
    const int nb = bx & 1, mb = bx >> 1;
    const int set = mb >> 7, bb = (mb >> 2) & 31, p = mb & 3, t0 = p << 6;
    const int n0 = nb << 7;
    if (tid < 128) pool[tid] = 0.f;
    const int w = tid >> 6, lane = tid & 63;
    const int rA = lane & 15, q4 = lane >> 4;

    floatx4 acc[4][2];
    for (int mi = 0; mi < 4; ++mi)
        for (int ni = 0; ni < 2; ++ni)
            acc[mi][ni] = (floatx4)(0.0f);

    const size_t arowbase = ((size_t)(set * 32 + bb) * 256 + t0) * 512;
    const int ch = tid & 15;
    for (int kc = 0; kc < 4; ++kc) {
        for (int i = 0; i < 4; ++i) {
            const int row = i * 16 + (tid >> 4);
            *(uint4*)(As + row * LDA + ch * 8) =
                *(const uint4*)(y1 + arowbase + (size_t)row * 512 + kc * 128 + ch * 8);
        }
        for (int i = 0; i < 8; ++i) {
            const int row = i * 16 + (tid >> 4);
            *(uint4*)(Bs + row * LDA + ch * 8) =
                *(const uint4*)(w2bf + (size_t)(n0 + row) * 512 + kc * 128 + ch * 8);
        }
        __syncthreads();
        for (int ks = 0; ks < 4; ++ks) {
            const int k0 = ks * 32 + q4 * 8;
            short8 a[4], bf[2];
            for (int mi = 0; mi < 4; ++mi)
                a[mi] = *(const short8*)(As + (mi * 16 + rA) * LDA + k0);
            for (int ni = 0; ni < 2; ++ni)
                bf[ni] = *(const short8*)(Bs + ((w * 2 + ni) * 16 + rA) * LDA + k0);
            for (int mi = 0; mi < 4; ++mi)
                for (int ni = 0; ni < 2; ++ni)
                    acc[mi][ni] = __builtin_amdgcn_mfma_f32_16x16x32_bf16(
                        a[mi], bf[ni], acc[mi][ni], 0, 0, 0);
        }
        __syncthreads();
    }
    // bias + relu + pool-sum over the 64 rows (one pool window per m-tile)
    for (int ni = 0; ni < 2; ++ni) {
        const int col = (w * 2 + ni) * 16 + rA;
        const float bias = b2[n0 + col];
        float s = 0.f;
        for (int mi = 0; mi < 4; ++mi)
            for (int r = 0; r < 4; ++r) {
                float v = acc[mi][ni][r] + bias;
                s += v > 0.f ? v : 0.f;
            }
        atomicAdd(&pool[col], s);
    }
    __syncthreads();
    if (tid < 128)
        y2[((size_t)(set * 32 + bb) * 4 + p) * 256 + n0 + tid] = pool[tid] * (1.f / 64.f);
}

// ---------------- VQ: argmin + commit + assemble transformer input ----------------
// grid 384 = (set,b,p); waves: w0/w1 instru rows 0-255/256-511, w2/w3 vocal
__global__ __launch_bounds__(256) void vq_kernel(
    const float* __restrict__ y2, const float* __restrict__ cbiT, const float* __restrict__ cbvT,
    const float* __restrict__ cbi, const float* __restrict__ cbv,
    const float* __restrict__ pos, float* __restrict__ ztr, float* __restrict__ accum)
{
    const int q = blockIdx.x;
    const int tid = threadIdx.x;
    const int set = q >> 7, bb = (q >> 2) & 31, p = q & 3;
    __shared__ float zloc[256];
    __shared__ float bestv[4];
    __shared__ int   besti[4];
    __shared__ int   code_sh[2];
    __shared__ float wsum2[4];
    zloc[tid] = y2[(size_t)q * 256 + tid];
    __syncthreads();
    const int w = tid >> 6, lane = tid & 63;
    const int half = w >> 1, sub = w & 1;
    const float* cbT = half ? cbvT : cbiT;
    const float* zh = zloc + half * 128;
    float best = 1e30f; int bidx = 0x7fffffff;
    for (int rr = 0; rr < 4; ++rr) {
        const int row = sub * 256 + rr * 64 + lane;
        float d2 = 0.f;
        for (int d = 0; d < 128; ++d) {
            float diff = zh[d] - cbT[d * 512 + row];
            d2 += diff * diff;
        }
        if (d2 < best) { best = d2; bidx = row; }
    }
    for (int off = 32; off > 0; off >>= 1) {
        float ov = __shfl_xor(best, off);
        int   oi = __shfl_xor(bidx, off);
        if (ov < best || (ov == best && oi < bidx)) { best = ov; bidx = oi; }
    }
    if (lane == 0) { bestv[w] = best; besti[w] = bidx; }
    __syncthreads();
    if (tid < 2) {
        float v0 = bestv[tid * 2], v1 = bestv[tid * 2 + 1];
        int   i0 = besti[tid * 2], i1 = besti[tid * 2 + 1];
        code_sh[tid] = (v1 < v0 || (v1 == v0 && i1 < i0)) ? i1 : i0;
    }
    __syncthreads();
    const int hh = tid >> 7, d = tid & 127;
    const int code = code_sh[hh];
    const float* cb = hh ? cbv : cbi;
    const float zq = cb[code * 128 + d];
    const float diff = zloc[hh * 128 + d] - zq;
    float sq = diff * diff;
    for (int off = 32; off > 0; off >>= 1) sq += __shfl_xor(sq, off);
    if (lane == 0) wsum2[w] = sq;
    const int s = (set * 2 + hh) * 4 + p;
    ztr[((size_t)bb * 24 + s) * 128 + d] = zq + pos[s * 128 + d];
    __syncthreads();
    if (tid == 0) atomicAdd(&accum[0], wsum2[0] + wsum2[1] + wsum2[2] + wsum2[3]);
}

// ---------------- transformer layer + lora_a, one block per batch ----------------
__device__ __forceinline__ void ln_rows(const float* src, float* dst,
                                        const float* g, const float* bta,
                                        int w, int lane)
{
    for (int rl = 0; rl < 3; ++rl) {
        int s = w + rl * 8;
        float v0 = src[s * 128 + lane], v1 = src[s * 128 + 64 + lane];
        float sum = v0 + v1, sq = v0 * v0 + v1 * v1;
        for (int off = 32; off > 0; off >>= 1) {
            sum += __shfl_xor(sum, off);
            sq  += __shfl_xor(sq, off);
        }
        float mu  = sum * (1.f / 128.f);
        float var = sq * (1.f / 128.f) - mu * mu;
        float inv = rsqrtf(var + 1e-5f);
        dst[s * 128 + lane]      = (v0 - mu) * inv * g[lane] + bta[lane];
        dst[s * 128 + 64 + lane] = (v1 - mu) * inv * g[64 + lane] + bta[64 + lane];
    }
}

__device__ __forceinline__ float dot128(const float* a, const float* b) {
    const float4* a4 = (const float4*)a;
    const float4* b4 = (const float4*)b;
    float acc = 0.f;
    for (int d = 0; d < 32; ++d) {
        float4 x = a4[d], y = b4[d];
        acc += x.x * y.x + x.y * y.y + x.z * y.z + x.w * y.w;
    }
    return acc;
}

__global__ __launch_bounds__(512) void transformer_kernel(
    const float* __restrict__ ztr,
    const float* __restrict__ aiw, const float* __restrict__ aib,
    const float* __restrict__ aow, const float* __restrict__ aob,
    const float* __restrict__ g1, const float* __restrict__ be1,
    const float* __restrict__ l1w, const float* __restrict__ l1b,
    const float* __restrict__ l2w, const float* __restrict__ l2b,
    const float* __restrict__ g2, const float* __restrict__ be2,
    const float* __restrict__ lora_a, float* __restrict__ hbuf)
{
    __shared__ float sm[14592];
    float* xb = sm;            // 3072, persistent
    float* qb = sm + 3072;     // q -> o -> ff_out
    float* kb = sm + 6144;     // k -> x2 (pre-LN1)
    float* vb = sm + 9216;     // v -> (hstrip region)
    float* ab = sm + 12288;    // attn 2304
    float* hstrip = sm + 9216; // 8 waves x 512 (overlaps vb+ab, both dead by FF)

    const int tid = threadIdx.x;
    const int bblk = blockIdx.x;
    const int w = tid >> 6, lane = tid & 63;

    for (int idx = tid; idx < 3072; idx += 512) xb[idx] = ztr[(size_t)bblk * 3072 + idx];
    __syncthreads();

    // qkv
    for (int o = tid; o < 9216; o += 512) {
        int s = o / 384, j = o % 384;
        float acc = aib[j] + dot128(xb + s * 128, aiw + j * 128);
        if (j < 128)      qb[s * 128 + j]       = acc;
        else if (j < 256) kb[s * 128 + j - 128] = acc;
        else              vb[s * 128 + j - 256] = acc;
    }
    __syncthreads();

    // scores
    for (int o = tid; o < 2304; o += 512) {
        int h = o / 576, r = o % 576, i = r / 24, j = r % 24;
        const float4* q4 = (const float4*)(qb + i * 128 + h * 32);
        const float4* k4 = (const float4*)(kb + j * 128 + h * 32);
        float acc = 0.f;
        for (int d = 0; d < 8; ++d) {
            float4 x = q4[d], y = k4[d];
            acc += x.x * y.x + x.y * y.y + x.z * y.z + x.w * y.w;
        }
        ab[(h * 24 + i) * 24 + j] = acc * 0.17677669529663687f;
    }
    __syncthreads();

    // softmax per (h, i) row
    if (tid < 96) {
        float* row = ab + tid * 24;
        float m = row[0];
        for (int j = 1; j < 24; ++j) m = row[j] > m ? row[j] : m;
        float ssum = 0.f;
        for (int j = 0; j < 24; ++j) { float e = __expf(row[j] - m); row[j] = e; ssum += e; }
        float inv = 1.f / ssum;
        for (int j = 0; j < 24; ++j) row[j] *= inv;
    }
    __syncthreads();

    // o = attn @ v   (into qb; q dead)
    for (int o = tid; o < 3072; o += 512) {
        int s = o >> 7, dg = o & 127, h = dg >> 5;
        const float* arow = ab + (h * 24 + s) * 24;
        float acc = 0.f;
        for (int j = 0; j < 24; ++j) acc += arow[j] * vb[j * 128 + dg];
        qb[o] = acc;
    }
    __syncthreads();

    // out-proj + residual (into kb; k dead)
    for (int o = tid; o < 3072; o += 512) {
        int s = o >> 7, d = o & 127;
        kb[o] = aob[d] + xb[o] + dot128(qb + s * 128, aow + d * 128);
    }
    __syncthreads();

    ln_rows(kb, xb, g1, be1, w, lane);   // LN1 -> xb
    __syncthreads();

    // FF, wave-per-row (rows w, w+8, w+16)
    for (int rl = 0; rl < 3; ++rl) {
        int s = w + rl * 8;
        for (int jj = 0; jj < 8; ++jj) {
            int f = jj * 64 + lane;
            float acc = l1b[f] + dot128(xb + s * 128, l1w + f * 128);
            hstrip[w * 512 + f] = acc > 0.f ? acc : 0.f;
        }
        __syncthreads();
        for (int dd = 0; dd < 2; ++dd) {
            int d = dd * 64 + lane;
            const float4* h4 = (const float4*)(hstrip + w * 512);
            const float4* w4 = (const float4*)(l2w + d * 512);
            float acc = l2b[d] + xb[s * 128 + d];
            for (int f = 0; f < 128; ++f) {
                float4 x = h4[f], y = w4[f];
                acc += x.x * y.x + x.y * y.y + x.z * y.z + x.w * y.w;
            }
            qb[s * 128 + d] = acc;
        }
        __syncthreads();
    }

    ln_rows(qb, xb, g2, be2, w, lane);   // LN2 -> xb (final flat)
    __syncthreads();

    // lora_a: h[b][r] = lora_a[r] . flat, wave w computes r = w
    float accr = 0.f;
    for (int idx = lane; idx < 3072; idx += 64)
        accr += lora_a[w * 3072 + idx] * xb[idx];
    for (int off = 32; off > 0; off >>= 1) accr += __shfl_xor(accr, off);
    if (lane == 0) hbuf[bblk * 8 + w] = accr;
}

// ---------------- logits + log-softmax + NLL, block per (t,c) ----------------
__global__ __launch_bounds__(256) void logits_kernel(
    const float* __restrict__ hbuf, const float* __restrict__ lora_b,
    const int* __restrict__ tokc, float* __restrict__ accum)
{
    const int tid = threadIdx.x;
    const int tcb = blockIdx.x;          // t*8 + c
    __shared__ float hl[256];
    __shared__ float wsum[4];
    __shared__ float ltok;
    hl[tid] = hbuf[tid];
    float wr[4][8];
    for (int i = 0; i < 4; ++i) {
        const float4* pw = (const float4*)(lora_b + ((size_t)tcb * 1024 + tid + 256 * i) * 8);
        float4 x = pw[0], y = pw[1];
        wr[i][0] = x.x; wr[i][1] = x.y; wr[i][2] = x.z; wr[i][3] = x.w;
        wr[i][4] = y.x; wr[i][5] = y.y; wr[i][6] = y.z; wr[i][7] = y.w;
    }
    __syncthreads();
    float nll = 0.f;
    for (int bb = 0; bb < 32; ++bb) {
        const int tv = tokc[bb * 2048 + tcb];
        const float* h = hl + bb * 8;
        float h0 = h[0], h1 = h[1], h2 = h[2], h3 = h[3];
        float h4 = h[4], h5 = h[5], h6 = h[6], h7 = h[7];
        float sl = 0.f;
        for (int i = 0; i < 4; ++i) {
            float lg = h0 * wr[i][0] + h1 * wr[i][1] + h2 * wr[i][2] + h3 * wr[i][3]
                     + h4 * wr[i][4] + h5 * wr[i][5] + h6 * wr[i][6] + h7 * wr[i][7];
            sl += __expf(lg);                 // |lg| << 1, no overflow; skip max-trick
            if (tid + 256 * i == tv) ltok = lg;
        }
        for (int off = 32; off > 0; off >>= 1) sl += __shfl_xor(sl, off);
        if ((tid & 63) == 0) wsum[tid >> 6] = sl;
        __syncthreads();
        if (tid == 0) nll += logf(wsum[0] + wsum[1] + wsum[2] + wsum[3]) - ltok;
        __syncthreads();
    }
    if (tid == 0) atomicAdd(&accum[1], nll);
}

__global__ void finalize_kernel(const float* __restrict__ accum, float* __restrict__ out) {
    out[0] = accum[1] * (1.f / 65536.f) + 0.05f * accum[0] * (1.f / 16384.f);
}

// ---------------- host ----------------
extern "C" void kernel_launch(void* const* d_in, const int* in_sizes, int n_in,
                              void* d_out, int out_size, void* d_ws, size_t ws_size,
                              hipStream_t stream) {
    const int*   tp   = (const int*)d_in[0];
    const int*   tcu  = (const int*)d_in[1];
    const int*   tn   = (const int*)d_in[2];
    const float* emb  = (const float*)d_in[3];
    const float* w1   = (const float*)d_in[4];
    const float* b1   = (const float*)d_in[5];
    const float* w2   = (const float*)d_in[6];
    const float* b2   = (const float*)d_in[7];
    const float* cbi  = (const float*)d_in[8];
    const float* cbv  = (const float*)d_in[9];
    const float* pos  = (const float*)d_in[10];
    const float* aiw  = (const float*)d_in[11];
    const float* aib  = (const float*)d_in[12];
    const float* aow  = (const float*)d_in[13];
    const float* aob  = (const float*)d_in[14];
    const float* g1   = (const float*)d_in[15];
    const float* be1  = (const float*)d_in[16];
    const float* l1w  = (const float*)d_in[17];
    const float* l1b  = (const float*)d_in[18];
    const float* l2w  = (const float*)d_in[19];
    const float* l2b  = (const float*)d_in[20];
    const float* g2   = (const float*)d_in[21];
    const float* be2  = (const float*)d_in[22];
    const float* lra  = (const float*)d_in[23];
    const float* lrb  = (const float*)d_in[24];

    char* wsb = (char*)d_ws;
    ushort* ebf  = (ushort*)(wsb + 0);            // 262144 B
    ushort* w1bf = (ushort*)(wsb + 262144);       // 3145728 B
    ushort* w2bf = (ushort*)(wsb + 3407872);      // 262144 B
    float*  cbiT = (float*)(wsb + 3670016);       // 262144 B
    float*  cbvT = (float*)(wsb + 3932160);       // 262144 B
    ushort* y1   = (ushort*)(wsb + 4194304);      // 25165824 B
    float*  y2   = (float*)(wsb + 29360128);      // 393216 B
    float*  ztr  = (float*)(wsb + 29753344);      // 393216 B
    float*  hbuf = (float*)(wsb + 30146560);      // 1024 B
    float*  accum= (float*)(wsb + 30147584);      // 8 B
    if (ws_size < 30147592) return;

    prep_misc<<<1536, 256, 0, stream>>>(emb, w2, cbi, cbv, ebf, w2bf, cbiT, cbvT, accum);
    prep_w1<<<6144, 256, 0, stream>>>(w1, w1bf);
    conv1_mfma<<<1536, 256, 0, stream>>>(tp, tcu, tn, ebf, w1bf, b1, y1);
    conv2_mfma<<<768, 256, 0, stream>>>(y1, w2bf, b2, y2);
    vq_kernel<<<384, 256, 0, stream>>>(y2, cbiT, cbvT, cbi, cbv, pos, ztr, accum);
    transformer_kernel<<<32, 512, 0, stream>>>(ztr, aiw, aib, aow, aob, g1, be1,
                                               l1w, l1b, l2w, l2b, g2, be2, lra, hbuf);
    logits_kernel<<<2048, 256, 0, stream>>>(hbuf, lrb, tcu, accum);
    finalize_kernel<<<1, 1, 0, stream>>>(accum, (float*)d_out);
}

// Round 2
// 438.613 us; speedup vs baseline: 1.9623x; 1.9623x over previous
//
#include <hip/hip_runtime.h>
#include <hip/hip_bf16.h>
#include <cstdint>
#include <cstddef>

typedef __attribute__((ext_vector_type(8))) short short8;
typedef __attribute__((ext_vector_type(4))) float floatx4;

// V=1024 C=8 T=256 BP=4 K=512 E=128 D=128 NB=24 NH=4 HD=32 FF=512 R=8 B=32

__device__ __forceinline__ ushort f2bf(float f) {
    union { float f; unsigned int u; } x; x.f = f;
    unsigned int r = (x.u + 0x7fffu + ((x.u >> 16) & 1u)) >> 16;
    return (ushort)r;
}
__device__ __forceinline__ float bf2f(ushort u) {
    union { unsigned int u; float f; } x; x.u = ((unsigned int)u) << 16;
    return x.f;
}

// ---------------- prep kernels ----------------
__global__ __launch_bounds__(256) void prep_misc(
    const float* __restrict__ emb, const float* __restrict__ w2,
    const float* __restrict__ cbi, const float* __restrict__ cbv,
    ushort* __restrict__ ebf, ushort* __restrict__ w2bf,
    float* __restrict__ cbiT, float* __restrict__ cbvT, float* __restrict__ accum)
{
    int idx = blockIdx.x * 256 + threadIdx.x;
    if (idx < 2) accum[idx] = 0.f;
    if (idx < 131072) {
        ebf[idx] = f2bf(emb[idx]);
    } else if (idx < 262144) {
        int j = idx - 131072;
        w2bf[j] = f2bf(w2[j]);
    } else if (idx < 327680) {
        int j = idx - 262144;
        cbiT[(j & 127) * 512 + (j >> 7)] = cbi[j];
    } else if (idx < 393216) {
        int j = idx - 327680;
        cbvT[(j & 127) * 512 + (j >> 7)] = cbv[j];
    }
}

// w1bf[kw][c][co][e]  <-  conv1_w[co][c*128+e][kw]
__global__ __launch_bounds__(256) void prep_w1(
    const float* __restrict__ w1, ushort* __restrict__ w1bf)
{
    int idx = blockIdx.x * 256 + threadIdx.x;   // < 1572864
    int e  = idx & 127;
    int co = (idx >> 7) & 511;
    int cc = (idx >> 16) & 7;
    int kw = idx >> 19;
    w1bf[idx] = f2bf(w1[(co * 1024 + cc * 128 + e) * 3 + kw]);
}

// transformer weights -> bf16 (row-major [out][in], no transpose needed)
__global__ __launch_bounds__(256) void prep_w_tf(
    const float* __restrict__ aiw, const float* __restrict__ aow,
    const float* __restrict__ l1w, const float* __restrict__ l2w,
    ushort* __restrict__ aiwbf, ushort* __restrict__ aowbf,
    ushort* __restrict__ l1wbf, ushort* __restrict__ l2wbf)
{
    int idx = blockIdx.x * 256 + threadIdx.x;   // < 196608
    if (idx < 49152)        aiwbf[idx]          = f2bf(aiw[idx]);
    else if (idx < 65536)   aowbf[idx - 49152]  = f2bf(aow[idx - 49152]);
    else if (idx < 131072)  l1wbf[idx - 65536]  = f2bf(l1w[idx - 65536]);
    else                    l2wbf[idx - 131072] = f2bf(l2w[idx - 131072]);
}

// ---------------- conv1: implicit GEMM, bf16 MFMA ----------------
__global__ __launch_bounds__(256) void conv1_mfma(
    const int* __restrict__ tp, const int* __restrict__ tcu, const int* __restrict__ tn,
    const ushort* __restrict__ ebf, const ushort* __restrict__ w1bf,
    const float* __restrict__ b1, ushort* __restrict__ y1)
{
    constexpr int LDA = 136;
    __shared__ ushort As[64 * LDA];
    __shared__ ushort Bs[128 * LDA];
    const int tid = threadIdx.x;
    const int bx = blockIdx.x;
    const int nb = bx & 3, mb = bx >> 2;
    const int set = mb >> 7, bb = (mb >> 2) & 31, t0 = (mb & 3) << 6;
    const int n0 = nb << 7;
    const int* tok = (set == 0) ? tp : ((set == 1) ? tcu : tn);
    const int w = tid >> 6, lane = tid & 63;
    const int rA = lane & 15, q4 = lane >> 4;

    floatx4 acc[4][2];
    for (int mi = 0; mi < 4; ++mi)
        for (int ni = 0; ni < 2; ++ni)
            acc[mi][ni] = (floatx4)(0.0f);

    const int ch = tid & 15;
    for (int kc = 0; kc < 24; ++kc) {
        const int kw = kc >> 3, cc = kc & 7;
        for (int i = 0; i < 4; ++i) {
            const int row = i * 16 + (tid >> 4);
            const int t = t0 + row + kw - 1;
            uint4 val = make_uint4(0u, 0u, 0u, 0u);
            if (t >= 0 && t < 256) {
                const int token = tok[bb * 2048 + t * 8 + cc];
                val = *(const uint4*)(ebf + token * 128 + ch * 8);
            }
            *(uint4*)(As + row * LDA + ch * 8) = val;
        }
        const ushort* wsrc = w1bf + ((size_t)((kw * 8 + cc) * 512 + n0)) * 128;
        for (int i = 0; i < 8; ++i) {
            const int row = i * 16 + (tid >> 4);
            *(uint4*)(Bs + row * LDA + ch * 8) = *(const uint4*)(wsrc + row * 128 + ch * 8);
        }
        __syncthreads();
        for (int ks = 0; ks < 4; ++ks) {
            const int k0 = ks * 32 + q4 * 8;
            short8 a[4], bf[2];
            for (int mi = 0; mi < 4; ++mi)
                a[mi] = *(const short8*)(As + (mi * 16 + rA) * LDA + k0);
            for (int ni = 0; ni < 2; ++ni)
                bf[ni] = *(const short8*)(Bs + ((w * 2 + ni) * 16 + rA) * LDA + k0);
            for (int mi = 0; mi < 4; ++mi)
                for (int ni = 0; ni < 2; ++ni)
                    acc[mi][ni] = __builtin_amdgcn_mfma_f32_16x16x32_bf16(
                        a[mi], bf[ni], acc[mi][ni], 0, 0, 0);
        }
        __syncthreads();
    }
    for (int ni = 0; ni < 2; ++ni) {
        const int co = n0 + (w * 2 + ni) * 16 + rA;
        const float bias = b1[co];
        for (int mi = 0; mi < 4; ++mi) {
            for (int r = 0; r < 4; ++r) {
                const int t = t0 + mi * 16 + q4 * 4 + r;
                float v = acc[mi][ni][r] + bias;
                v = v > 0.f ? v : 0.f;
                y1[((size_t)(set * 32 + bb) * 256 + t) * 512 + co] = f2bf(v);
            }
        }
    }
}

// ---------------- conv2 + avgpool(64): bf16 MFMA ----------------
__global__ __launch_bounds__(256) void conv2_mfma(
    const ushort* __restrict__ y1, const ushort* __restrict__ w2bf,
    const float* __restrict__ b2, float* __restrict__ y2)
{
    constexpr int LDA = 136;
    __shared__ ushort As[64 * LDA];
    __shared__ ushort Bs[128 * LDA];
    __shared__ float pool[128];
    const int tid = threadIdx.x;
    const int bx = blockIdx.x;
    const int nb = bx & 1, mb = bx >> 1;
    const int set = mb >> 7, bb = (mb >> 2) & 31, p = mb & 3, t0 = p << 6;
    const int n0 = nb << 7;
    if (tid < 128) pool[tid] = 0.f;
    const int w = tid >> 6, lane = tid & 63;
    const int rA = lane & 15, q4 = lane >> 4;

    floatx4 acc[4][2];
    for (int mi = 0; mi < 4; ++mi)
        for (int ni = 0; ni < 2; ++ni)
            acc[mi][ni] = (floatx4)(0.0f);

    const size_t arowbase = ((size_t)(set * 32 + bb) * 256 + t0) * 512;
    const int ch = tid & 15;
    for (int kc = 0; kc < 4; ++kc) {
        for (int i = 0; i < 4; ++i) {
            const int row = i * 16 + (tid >> 4);
            *(uint4*)(As + row * LDA + ch * 8) =
                *(const uint4*)(y1 + arowbase + (size_t)row * 512 + kc * 128 + ch * 8);
        }
        for (int i = 0; i < 8; ++i) {
            const int row = i * 16 + (tid >> 4);
            *(uint4*)(Bs + row * LDA + ch * 8) =
                *(const uint4*)(w2bf + (size_t)(n0 + row) * 512 + kc * 128 + ch * 8);
        }
        __syncthreads();
        for (int ks = 0; ks < 4; ++ks) {
            const int k0 = ks * 32 + q4 * 8;
            short8 a[4], bf[2];
            for (int mi = 0; mi < 4; ++mi)
                a[mi] = *(const short8*)(As + (mi * 16 + rA) * LDA + k0);
            for (int ni = 0; ni < 2; ++ni)
                bf[ni] = *(const short8*)(Bs + ((w * 2 + ni) * 16 + rA) * LDA + k0);
            for (int mi = 0; mi < 4; ++mi)
                for (int ni = 0; ni < 2; ++ni)
                    acc[mi][ni] = __builtin_amdgcn_mfma_f32_16x16x32_bf16(
                        a[mi], bf[ni], acc[mi][ni], 0, 0, 0);
        }
        __syncthreads();
    }
    for (int ni = 0; ni < 2; ++ni) {
        const int col = (w * 2 + ni) * 16 + rA;
        const float bias = b2[n0 + col];
        float s = 0.f;
        for (int mi = 0; mi < 4; ++mi)
            for (int r = 0; r < 4; ++r) {
                float v = acc[mi][ni][r] + bias;
                s += v > 0.f ? v : 0.f;
            }
        atomicAdd(&pool[col], s);
    }
    __syncthreads();
    if (tid < 128)
        y2[((size_t)(set * 32 + bb) * 4 + p) * 256 + n0 + tid] = pool[tid] * (1.f / 64.f);
}

// ---------------- VQ: argmin + commit + assemble transformer input ----------------
__global__ __launch_bounds__(256) void vq_kernel(
    const float* __restrict__ y2, const float* __restrict__ cbiT, const float* __restrict__ cbvT,
    const float* __restrict__ cbi, const float* __restrict__ cbv,
    const float* __restrict__ pos, float* __restrict__ ztr, ushort* __restrict__ xbf,
    float* __restrict__ accum)
{
    const int q = blockIdx.x;
    const int tid = threadIdx.x;
    const int set = q >> 7, bb = (q >> 2) & 31, p = q & 3;
    __shared__ float zloc[256];
    __shared__ float bestv[4];
    __shared__ int   besti[4];
    __shared__ int   code_sh[2];
    __shared__ float wsum2[4];
    zloc[tid] = y2[(size_t)q * 256 + tid];
    __syncthreads();
    const int w = tid >> 6, lane = tid & 63;
    const int half = w >> 1, sub = w & 1;
    const float* cbT = half ? cbvT : cbiT;
    const float* zh = zloc + half * 128;
    float best = 1e30f; int bidx = 0x7fffffff;
    for (int rr = 0; rr < 4; ++rr) {
        const int row = sub * 256 + rr * 64 + lane;
        float d2 = 0.f;
        for (int d = 0; d < 128; ++d) {
            float diff = zh[d] - cbT[d * 512 + row];
            d2 += diff * diff;
        }
        if (d2 < best) { best = d2; bidx = row; }
    }
    for (int off = 32; off > 0; off >>= 1) {
        float ov = __shfl_xor(best, off);
        int   oi = __shfl_xor(bidx, off);
        if (ov < best || (ov == best && oi < bidx)) { best = ov; bidx = oi; }
    }
    if (lane == 0) { bestv[w] = best; besti[w] = bidx; }
    __syncthreads();
    if (tid < 2) {
        float v0 = bestv[tid * 2], v1 = bestv[tid * 2 + 1];
        int   i0 = besti[tid * 2], i1 = besti[tid * 2 + 1];
        code_sh[tid] = (v1 < v0 || (v1 == v0 && i1 < i0)) ? i1 : i0;
    }
    __syncthreads();
    const int hh = tid >> 7, d = tid & 127;
    const int code = code_sh[hh];
    const float* cb = hh ? cbv : cbi;
    const float zq = cb[code * 128 + d];
    const float diff = zloc[hh * 128 + d] - zq;
    float sq = diff * diff;
    for (int off = 32; off > 0; off >>= 1) sq += __shfl_xor(sq, off);
    if (lane == 0) wsum2[w] = sq;
    const int s = (set * 2 + hh) * 4 + p;
    const float val = zq + pos[s * 128 + d];
    ztr[((size_t)bb * 24 + s) * 128 + d] = val;
    xbf[((size_t)bb * 24 + s) * 128 + d] = f2bf(val);
    __syncthreads();
    if (tid == 0) atomicAdd(&accum[0], wsum2[0] + wsum2[1] + wsum2[2] + wsum2[3]);
}

// ---------------- generic 64x64-tile bf16 GEMM: C = A(MxK) . B(NxK)^T ----------------
template<int KTOT, int NTOT, int RELU, int OUTBF>
__global__ __launch_bounds__(256) void gemm64_kernel(
    const ushort* __restrict__ A, const ushort* __restrict__ Bw,
    const float* __restrict__ bias, void* __restrict__ Co)
{
    constexpr int NBLK = NTOT / 64;
    constexpr int LDA = 136;
    __shared__ ushort As[64 * LDA];
    __shared__ ushort Bs[64 * LDA];
    const int tid = threadIdx.x;
    const int mblk = blockIdx.x / NBLK, nblk = blockIdx.x % NBLK;
    const int m0 = mblk * 64, n0 = nblk * 64;
    const int w = tid >> 6, lane = tid & 63;
    const int rA = lane & 15, q4 = lane >> 4;
    const int ch = tid & 15, rowst = tid >> 4;

    floatx4 acc[4];
    for (int mi = 0; mi < 4; ++mi) acc[mi] = (floatx4)(0.f);

    for (int kc = 0; kc < KTOT / 128; ++kc) {
        for (int i = 0; i < 4; ++i) {
            const int row = i * 16 + rowst;
            *(uint4*)(As + row * LDA + ch * 8) =
                *(const uint4*)(A + (size_t)(m0 + row) * KTOT + kc * 128 + ch * 8);
            *(uint4*)(Bs + row * LDA + ch * 8) =
                *(const uint4*)(Bw + (size_t)(n0 + row) * KTOT + kc * 128 + ch * 8);
        }
        __syncthreads();
        for (int ks = 0; ks < 4; ++ks) {
            const int k0 = ks * 32 + q4 * 8;
            short8 bfr = *(const short8*)(Bs + (w * 16 + rA) * LDA + k0);
            for (int mi = 0; mi < 4; ++mi) {
                short8 a = *(const short8*)(As + (mi * 16 + rA) * LDA + k0);
                acc[mi] = __builtin_amdgcn_mfma_f32_16x16x32_bf16(a, bfr, acc[mi], 0, 0, 0);
            }
        }
        __syncthreads();
    }
    const int col = n0 + w * 16 + rA;
    const float bs = bias[col];
    for (int mi = 0; mi < 4; ++mi) {
        for (int r = 0; r < 4; ++r) {
            const int row = m0 + mi * 16 + q4 * 4 + r;
            float vv = acc[mi][r] + bs;
            if (RELU) vv = vv > 0.f ? vv : 0.f;
            if (OUTBF) ((ushort*)Co)[(size_t)row * NTOT + col] = f2bf(vv);
            else       ((float*)Co)[(size_t)row * NTOT + col]  = vv;
        }
    }
}

// ---------------- 64x128-tile GEMM + residual + LayerNorm epilogue ----------------
template<int KTOT, int WRITE_F32>
__global__ __launch_bounds__(256) void gemm_ln_kernel(
    const ushort* __restrict__ A, const ushort* __restrict__ Bw,
    const float* __restrict__ bias, const float* __restrict__ resid,
    const float* __restrict__ g, const float* __restrict__ beta,
    ushort* __restrict__ outbf, float* __restrict__ outf)
{
    constexpr int LDA = 136;
    __shared__ ushort As[64 * LDA];
    __shared__ ushort Bs[128 * LDA];
    __shared__ float ps[64 * 4], pq[64 * 4], muv[64], invv[64];
    const int tid = threadIdx.x;
    const int m0 = blockIdx.x * 64;
    const int w = tid >> 6, lane = tid & 63;
    const int rA = lane & 15, q4 = lane >> 4;
    const int ch = tid & 15, rowst = tid >> 4;

    floatx4 acc[4][2];
    for (int mi = 0; mi < 4; ++mi)
        for (int ni = 0; ni < 2; ++ni)
            acc[mi][ni] = (floatx4)(0.f);

    for (int kc = 0; kc < KTOT / 128; ++kc) {
        for (int i = 0; i < 4; ++i) {
            const int row = i * 16 + rowst;
            *(uint4*)(As + row * LDA + ch * 8) =
                *(const uint4*)(A + (size_t)(m0 + row) * KTOT + kc * 128 + ch * 8);
        }
        for (int i = 0; i < 8; ++i) {
            const int row = i * 16 + rowst;
            *(uint4*)(Bs + row * LDA + ch * 8) =
                *(const uint4*)(Bw + (size_t)row * KTOT + kc * 128 + ch * 8);
        }
        __syncthreads();
        for (int ks = 0; ks < 4; ++ks) {
            const int k0 = ks * 32 + q4 * 8;
            short8 a[4], bf[2];
            for (int mi = 0; mi < 4; ++mi)
                a[mi] = *(const short8*)(As + (mi * 16 + rA) * LDA + k0);
            for (int ni = 0; ni < 2; ++ni)
                bf[ni] = *(const short8*)(Bs + ((w * 2 + ni) * 16 + rA) * LDA + k0);
            for (int mi = 0; mi < 4; ++mi)
                for (int ni = 0; ni < 2; ++ni)
                    acc[mi][ni] = __builtin_amdgcn_mfma_f32_16x16x32_bf16(
                        a[mi], bf[ni], acc[mi][ni], 0, 0, 0);
        }
        __syncthreads();
    }
    // add bias + residual in-register
    for (int ni = 0; ni < 2; ++ni) {
        const int col = (w * 2 + ni) * 16 + rA;
        const float bs = bias[col];
        for (int mi = 0; mi < 4; ++mi)
            for (int r = 0; r < 4; ++r) {
                const int row = m0 + mi * 16 + q4 * 4 + r;
                acc[mi][ni][r] += bs + resid[(size_t)row * 128 + col];
            }
    }
    // per-row partial sums: reduce over rA (16 lanes), both ni in-register
    for (int mi = 0; mi < 4; ++mi)
        for (int r = 0; r < 4; ++r) {
            float s  = acc[mi][0][r] + acc[mi][1][r];
            float sq = acc[mi][0][r] * acc[mi][0][r] + acc[mi][1][r] * acc[mi][1][r];
            for (int off = 1; off < 16; off <<= 1) {
                s  += __shfl_xor(s, off);
                sq += __shfl_xor(sq, off);
            }
            if (rA == 0) {
                const int rl = mi * 16 + q4 * 4 + r;
                ps[rl * 4 + w] = s;
                pq[rl * 4 + w] = sq;
            }
        }
    __syncthreads();
    if (tid < 64) {
        float s  = ps[tid * 4] + ps[tid * 4 + 1] + ps[tid * 4 + 2] + ps[tid * 4 + 3];
        float sq = pq[tid * 4] + pq[tid * 4 + 1] + pq[tid * 4 + 2] + pq[tid * 4 + 3];
        float mu = s * (1.f / 128.f);
        float var = sq * (1.f / 128.f) - mu * mu;
        muv[tid] = mu;
        invv[tid] = rsqrtf(var + 1e-5f);
    }
    __syncthreads();
    for (int ni = 0; ni < 2; ++ni) {
        const int col = (w * 2 + ni) * 16 + rA;
        const float gg = g[col], bb = beta[col];
        for (int mi = 0; mi < 4; ++mi)
            for (int r = 0; r < 4; ++r) {
                const int rl = mi * 16 + q4 * 4 + r;
                const int row = m0 + rl;
                float v = (acc[mi][ni][r] - muv[rl]) * invv[rl] * gg + bb;
                outbf[(size_t)row * 128 + col] = f2bf(v);
                if (WRITE_F32) outf[(size_t)row * 128 + col] = v;
            }
    }
}

// ---------------- attention: one block per (b, h) ----------------
__global__ __launch_bounds__(64) void attn_kernel(
    const float* __restrict__ qkvb, ushort* __restrict__ obuf)
{
    const int bh = blockIdx.x;
    const int b = bh >> 2, h = bh & 3;
    const int tid = threadIdx.x;
    __shared__ float q[24 * 32], k[24 * 32], v[24 * 32], sc[24 * 24];
    for (int i = 0; i < 12; ++i) {
        const int idx = i * 64 + tid;
        const int s = idx >> 5, d = idx & 31;
        const size_t base = ((size_t)(b * 24 + s)) * 384 + h * 32 + d;
        q[idx] = qkvb[base];
        k[idx] = qkvb[base + 128];
        v[idx] = qkvb[base + 256];
    }
    __syncthreads();
    for (int i = 0; i < 9; ++i) {
        const int e = i * 64 + tid;
        const int si = e / 24, j = e - si * 24;
        float a = 0.f;
        for (int d = 0; d < 32; ++d) a += q[si * 32 + d] * k[j * 32 + d];
        sc[si * 24 + j] = a * 0.17677669529663687f;
    }
    __syncthreads();
    if (tid < 24) {
        float* row = sc + tid * 24;
        float m = row[0];
        for (int j = 1; j < 24; ++j) m = row[j] > m ? row[j] : m;
        float ssum = 0.f;
        for (int j = 0; j < 24; ++j) { float e = __expf(row[j] - m); row[j] = e; ssum += e; }
        float inv = 1.f / ssum;
        for (int j = 0; j < 24; ++j) row[j] *= inv;
    }
    __syncthreads();
    for (int i = 0; i < 12; ++i) {
        const int idx = i * 64 + tid;
        const int s = idx >> 5, d = idx & 31;
        float a = 0.f;
        for (int j = 0; j < 24; ++j) a += sc[s * 24 + j] * v[j * 32 + d];
        obuf[((size_t)(b * 24 + s)) * 128 + h * 32 + d] = f2bf(a);
    }
}

// ---------------- lora_a: h[b][r] = lora_a[r] . z[b], grid 32 ----------------
__global__ __launch_bounds__(256) void lora_kernel(
    const ushort* __restrict__ zbf, const float* __restrict__ lora_a,
    float* __restrict__ hbuf)
{
    const int b = blockIdx.x;
    const int tid = threadIdx.x;
    const int w = tid >> 6, lane = tid & 63;
    __shared__ float zl[3072];
    for (int idx = tid; idx < 3072; idx += 256) zl[idx] = bf2f(zbf[(size_t)b * 3072 + idx]);
    __syncthreads();
    for (int rr = 0; rr < 2; ++rr) {
        const int r = w + rr * 4;
        float acc = 0.f;
        for (int idx = lane; idx < 3072; idx += 64)
            acc += lora_a[(size_t)r * 3072 + idx] * zl[idx];
        for (int off = 32; off > 0; off >>= 1) acc += __shfl_xor(acc, off);
        if (lane == 0) hbuf[b * 8 + r] = acc;
    }
}

// ---------------- logits + log-softmax + NLL, block per (t,c) ----------------
__global__ __launch_bounds__(256) void logits_kernel(
    const float* __restrict__ hbuf, const float* __restrict__ lora_b,
    const int* __restrict__ tokc, float* __restrict__ accum)
{
    const int tid = threadIdx.x;
    const int tcb = blockIdx.x;          // t*8 + c
    __shared__ float hl[256];
    __shared__ float wsum[4];
    __shared__ float ltok;
    hl[tid] = hbuf[tid];
    float wr[4][8];
    for (int i = 0; i < 4; ++i) {
        const float4* pw = (const float4*)(lora_b + ((size_t)tcb * 1024 + tid + 256 * i) * 8);
        float4 x = pw[0], y = pw[1];
        wr[i][0] = x.x; wr[i][1] = x.y; wr[i][2] = x.z; wr[i][3] = x.w;
        wr[i][4] = y.x; wr[i][5] = y.y; wr[i][6] = y.z; wr[i][7] = y.w;
    }
    __syncthreads();
    float nll = 0.f;
    for (int bb = 0; bb < 32; ++bb) {
        const int tv = tokc[bb * 2048 + tcb];
        const float* h = hl + bb * 8;
        float h0 = h[0], h1 = h[1], h2 = h[2], h3 = h[3];
        float h4 = h[4], h5 = h[5], h6 = h[6], h7 = h[7];
        float sl = 0.f;
        for (int i = 0; i < 4; ++i) {
            float lg = h0 * wr[i][0] + h1 * wr[i][1] + h2 * wr[i][2] + h3 * wr[i][3]
                     + h4 * wr[i][4] + h5 * wr[i][5] + h6 * wr[i][6] + h7 * wr[i][7];
            sl += __expf(lg);
            if (tid + 256 * i == tv) ltok = lg;
        }
        for (int off = 32; off > 0; off >>= 1) sl += __shfl_xor(sl, off);
        if ((tid & 63) == 0) wsum[tid >> 6] = sl;
        __syncthreads();
        if (tid == 0) nll += logf(wsum[0] + wsum[1] + wsum[2] + wsum[3]) - ltok;
        __syncthreads();
    }
    if (tid == 0) atomicAdd(&accum[1], nll);
}

__global__ void finalize_kernel(const float* __restrict__ accum, float* __restrict__ out) {
    out[0] = accum[1] * (1.f / 65536.f) + 0.05f * accum[0] * (1.f / 16384.f);
}

// ---------------- host ----------------
extern "C" void kernel_launch(void* const* d_in, const int* in_sizes, int n_in,
                              void* d_out, int out_size, void* d_ws, size_t ws_size,
                              hipStream_t stream) {
    const int*   tp   = (const int*)d_in[0];
    const int*   tcu  = (const int*)d_in[1];
    const int*   tn   = (const int*)d_in[2];
    const float* emb  = (const float*)d_in[3];
    const float* w1   = (const float*)d_in[4];
    const float* b1   = (const float*)d_in[5];
    const float* w2   = (const float*)d_in[6];
    const float* b2   = (const float*)d_in[7];
    const float* cbi  = (const float*)d_in[8];
    const float* cbv  = (const float*)d_in[9];
    const float* pos  = (const float*)d_in[10];
    const float* aiw  = (const float*)d_in[11];
    const float* aib  = (const float*)d_in[12];
    const float* aow  = (const float*)d_in[13];
    const float* aob  = (const float*)d_in[14];
    const float* g1   = (const float*)d_in[15];
    const float* be1  = (const float*)d_in[16];
    const float* l1w  = (const float*)d_in[17];
    const float* l1b  = (const float*)d_in[18];
    const float* l2w  = (const float*)d_in[19];
    const float* l2b  = (const float*)d_in[20];
    const float* g2   = (const float*)d_in[21];
    const float* be2  = (const float*)d_in[22];
    const float* lra  = (const float*)d_in[23];
    const float* lrb  = (const float*)d_in[24];

    char* wsb = (char*)d_ws;
    ushort* ebf  = (ushort*)(wsb + 0);            // 262144 B
    ushort* w1bf = (ushort*)(wsb + 262144);       // 3145728 B
    ushort* w2bf = (ushort*)(wsb + 3407872);      // 262144 B
    float*  cbiT = (float*)(wsb + 3670016);       // 262144 B
    float*  cbvT = (float*)(wsb + 3932160);       // 262144 B
    ushort* y1   = (ushort*)(wsb + 4194304);      // 25165824 B (dead after conv2)
    float*  y2   = (float*)(wsb + 29360128);      // 393216 B
    float*  ztr  = (float*)(wsb + 29753344);      // 393216 B
    float*  hbuf = (float*)(wsb + 30146560);      // 1024 B
    float*  accum= (float*)(wsb + 30147584);      // 64 B
    ushort* aiwbf= (ushort*)(wsb + 30147648);     // 98304 B
    ushort* aowbf= (ushort*)(wsb + 30245952);     // 32768 B
    ushort* l1wbf= (ushort*)(wsb + 30278720);     // 131072 B
    ushort* l2wbf= (ushort*)(wsb + 30409792);     // 131072 B -> 30540864
    if (ws_size < 30540864) return;

    // transformer temporaries alias the (dead-by-then) y1 region
    float*  qkvb = (float*)(wsb + 4194304);       // 1179648 B
    ushort* obuf = (ushort*)(wsb + 5373952);      // 196608 B
    ushort* x1bf = (ushort*)(wsb + 5570560);      // 196608 B
    float*  x1f  = (float*)(wsb + 5767168);       // 393216 B
    ushort* hff  = (ushort*)(wsb + 6160384);      // 786432 B
    ushort* zbf  = (ushort*)(wsb + 6946816);      // 196608 B
    ushort* xbf  = (ushort*)(wsb + 7143424);      // 196608 B

    prep_misc<<<1536, 256, 0, stream>>>(emb, w2, cbi, cbv, ebf, w2bf, cbiT, cbvT, accum);
    prep_w1<<<6144, 256, 0, stream>>>(w1, w1bf);
    prep_w_tf<<<768, 256, 0, stream>>>(aiw, aow, l1w, l2w, aiwbf, aowbf, l1wbf, l2wbf);
    conv1_mfma<<<1536, 256, 0, stream>>>(tp, tcu, tn, ebf, w1bf, b1, y1);
    conv2_mfma<<<768, 256, 0, stream>>>(y1, w2bf, b2, y2);
    vq_kernel<<<384, 256, 0, stream>>>(y2, cbiT, cbvT, cbi, cbv, pos, ztr, xbf, accum);
    gemm64_kernel<128, 384, 0, 0><<<72, 256, 0, stream>>>(xbf, aiwbf, aib, qkvb);
    attn_kernel<<<128, 64, 0, stream>>>(qkvb, obuf);
    gemm_ln_kernel<128, 1><<<12, 256, 0, stream>>>(obuf, aowbf, aob, ztr, g1, be1, x1bf, x1f);
    gemm64_kernel<128, 512, 1, 1><<<96, 256, 0, stream>>>(x1bf, l1wbf, l1b, hff);
    gemm_ln_kernel<512, 0><<<12, 256, 0, stream>>>(hff, l2wbf, l2b, x1f, g2, be2, zbf, nullptr);
    lora_kernel<<<32, 256, 0, stream>>>(zbf, lra, hbuf);
    logits_kernel<<<2048, 256, 0, stream>>>(hbuf, lrb, tcu, accum);
    finalize_kernel<<<1, 1, 0, stream>>>(accum, (float*)d_out);
}

// Round 3
// 404.379 us; speedup vs baseline: 2.1284x; 1.0847x over previous
//
#include <hip/hip_runtime.h>
#include <hip/hip_bf16.h>
#include <cstdint>
#include <cstddef>

typedef __attribute__((ext_vector_type(8))) short short8;
typedef __attribute__((ext_vector_type(4))) float floatx4;

// V=1024 C=8 T=256 BP=4 K=512 E=128 D=128 NB=24 NH=4 HD=32 FF=512 R=8 B=32

__device__ __forceinline__ ushort f2bf(float f) {
    union { float f; unsigned int u; } x; x.f = f;
    unsigned int r = (x.u + 0x7fffu + ((x.u >> 16) & 1u)) >> 16;
    return (ushort)r;
}
__device__ __forceinline__ float bf2f(ushort u) {
    union { unsigned int u; float f; } x; x.u = ((unsigned int)u) << 16;
    return x.f;
}

// ---------------- single merged prep kernel ----------------
__global__ __launch_bounds__(256) void prep_all(
    const float* __restrict__ emb, const float* __restrict__ w1,
    const float* __restrict__ w2, const float* __restrict__ cbi,
    const float* __restrict__ cbv, const float* __restrict__ aiw,
    const float* __restrict__ aow, const float* __restrict__ l1w,
    const float* __restrict__ l2w,
    ushort* __restrict__ ebf, ushort* __restrict__ w1bf, ushort* __restrict__ w2bf,
    float* __restrict__ cbiT, float* __restrict__ cbvT,
    ushort* __restrict__ aiwbf, ushort* __restrict__ aowbf,
    ushort* __restrict__ l1wbf, ushort* __restrict__ l2wbf,
    float* __restrict__ accum)
{
    int idx = blockIdx.x * 256 + threadIdx.x;
    if (idx < 4) accum[idx] = 0.f;
    if (idx < 131072) {
        ebf[idx] = f2bf(emb[idx]);
    } else if (idx < 262144) {
        int j = idx - 131072; w2bf[j] = f2bf(w2[j]);
    } else if (idx < 327680) {
        int j = idx - 262144; cbiT[(j & 127) * 512 + (j >> 7)] = cbi[j];
    } else if (idx < 393216) {
        int j = idx - 327680; cbvT[(j & 127) * 512 + (j >> 7)] = cbv[j];
    } else if (idx < 442368) {
        int j = idx - 393216; aiwbf[j] = f2bf(aiw[j]);
    } else if (idx < 475136) {
        int j = idx - 442368; aowbf[j] = f2bf(aow[j]);
    } else if (idx < 540672) {
        int j = idx - 475136; l1wbf[j] = f2bf(l1w[j]);
    } else if (idx < 606208) {
        int j = idx - 540672; l2wbf[j] = f2bf(l2w[j]);
    } else if (idx < 2179072) {
        int j = idx - 606208;   // w1bf[kw][c][co][e] <- conv1_w[co][c*128+e][kw]
        int e  = j & 127;
        int co = (j >> 7) & 511;
        int cc = (j >> 16) & 7;
        int kw = j >> 19;
        w1bf[j] = f2bf(w1[(co * 1024 + cc * 128 + e) * 3 + kw]);
    }
}

// ---------------- conv1: implicit GEMM, 128x128 tile, A-halo reuse over kw ----------------
__global__ __launch_bounds__(512, 4) void conv1_mfma(
    const int* __restrict__ tp, const int* __restrict__ tcu, const int* __restrict__ tn,
    const ushort* __restrict__ ebf, const ushort* __restrict__ w1bf,
    const float* __restrict__ b1, ushort* __restrict__ y1)
{
    constexpr int LDA = 136;
    __shared__ ushort As[130 * LDA];   // 130 t-rows (2-row halo) x 128 e
    __shared__ ushort Bs[128 * LDA];   // 128 co x 128 e
    __shared__ int tokL[130 * 8];
    const int tid = threadIdx.x;
    const int bx = blockIdx.x;
    const int nb = bx & 3, mb = bx >> 2;                 // 4 n-tiles, 192 m-tiles
    const int set = mb >> 6, rem = mb & 63, bb = rem >> 1, t0 = (rem & 1) << 7;
    const int n0 = nb << 7;
    const int* tok = (set == 0) ? tp : ((set == 1) ? tcu : tn);

    // preload all token indices once (kills the dependent int-load chain)
    for (int idx = tid; idx < 1040; idx += 512) {
        const int row = idx >> 3, cc = idx & 7;
        const int gt = t0 + row - 1;
        tokL[idx] = (gt >= 0 && gt < 256) ? tok[bb * 2048 + gt * 8 + cc] : -1;
    }

    const int w = tid >> 6, lane = tid & 63;
    const int wm = w & 1, wn = w >> 1;                   // 2 m-groups x 4 n-groups
    const int rA = lane & 15, q4 = lane >> 4;
    const int ch = tid & 15, rowst = tid >> 4;           // 32 rows per staging pass

    floatx4 acc[4][2];
    for (int mi = 0; mi < 4; ++mi)
        for (int ni = 0; ni < 2; ++ni)
            acc[mi][ni] = (floatx4)(0.0f);

    __syncthreads();

    for (int cc = 0; cc < 8; ++cc) {
        // stage A once per cc (reused by all 3 kw)
        for (int p = 0; p < 5; ++p) {
            const int row = p * 32 + rowst;
            if (row < 130) {
                const int tk = tokL[row * 8 + cc];
                uint4 val = make_uint4(0u, 0u, 0u, 0u);
                if (tk >= 0) val = *(const uint4*)(ebf + tk * 128 + ch * 8);
                *(uint4*)(As + row * LDA + ch * 8) = val;
            }
        }
        for (int kw = 0; kw < 3; ++kw) {
            const ushort* wsrc = w1bf + ((size_t)((kw * 8 + cc) * 512 + n0)) * 128;
            for (int p = 0; p < 4; ++p) {
                const int row = p * 32 + rowst;
                *(uint4*)(Bs + row * LDA + ch * 8) = *(const uint4*)(wsrc + row * 128 + ch * 8);
            }
            __syncthreads();
            for (int ks = 0; ks < 4; ++ks) {
                const int k0 = ks * 32 + q4 * 8;
                short8 a[4], bfr[2];
                for (int mi = 0; mi < 4; ++mi)
                    a[mi] = *(const short8*)(As + (wm * 64 + mi * 16 + rA + kw) * LDA + k0);
                for (int ni = 0; ni < 2; ++ni)
                    bfr[ni] = *(const short8*)(Bs + (wn * 32 + ni * 16 + rA) * LDA + k0);
                for (int mi = 0; mi < 4; ++mi)
                    for (int ni = 0; ni < 2; ++ni)
                        acc[mi][ni] = __builtin_amdgcn_mfma_f32_16x16x32_bf16(
                            a[mi], bfr[ni], acc[mi][ni], 0, 0, 0);
            }
            __syncthreads();
        }
    }
    for (int ni = 0; ni < 2; ++ni) {
        const int co = n0 + wn * 32 + ni * 16 + rA;
        const float bias = b1[co];
        for (int mi = 0; mi < 4; ++mi) {
            for (int r = 0; r < 4; ++r) {
                const int t = t0 + wm * 64 + mi * 16 + q4 * 4 + r;
                float v = acc[mi][ni][r] + bias;
                v = v > 0.f ? v : 0.f;
                y1[((size_t)(set * 32 + bb) * 256 + t) * 512 + co] = f2bf(v);
            }
        }
    }
}

// ---------------- conv2 + avgpool(64): 128x128 tile ----------------
__global__ __launch_bounds__(512, 4) void conv2_mfma(
    const ushort* __restrict__ y1, const ushort* __restrict__ w2bf,
    const float* __restrict__ b2, float* __restrict__ y2)
{
    constexpr int LDA = 136;
    __shared__ ushort As[128 * LDA];
    __shared__ ushort Bs[128 * LDA];
    __shared__ float pool[256];
    const int tid = threadIdx.x;
    const int bx = blockIdx.x;
    const int nb = bx & 1, mb = bx >> 1;                 // 2 n-tiles, 192 m-tiles
    const int set = mb >> 6, rem = mb & 63, bb = rem >> 1, t0 = (rem & 1) << 7;
    const int n0 = nb << 7;
    const int w = tid >> 6, lane = tid & 63;
    const int wm = w & 1, wn = w >> 1;
    const int rA = lane & 15, q4 = lane >> 4;
    const int ch = tid & 15, rowst = tid >> 4;

    floatx4 acc[4][2];
    for (int mi = 0; mi < 4; ++mi)
        for (int ni = 0; ni < 2; ++ni)
            acc[mi][ni] = (floatx4)(0.0f);

    const size_t arowbase = ((size_t)(set * 32 + bb) * 256 + t0) * 512;
    for (int kc = 0; kc < 4; ++kc) {
        for (int p = 0; p < 4; ++p) {
            const int row = p * 32 + rowst;
            *(uint4*)(As + row * LDA + ch * 8) =
                *(const uint4*)(y1 + arowbase + (size_t)row * 512 + kc * 128 + ch * 8);
            *(uint4*)(Bs + row * LDA + ch * 8) =
                *(const uint4*)(w2bf + (size_t)(n0 + row) * 512 + kc * 128 + ch * 8);
        }
        __syncthreads();
        for (int ks = 0; ks < 4; ++ks) {
            const int k0 = ks * 32 + q4 * 8;
            short8 a[4], bfr[2];
            for (int mi = 0; mi < 4; ++mi)
                a[mi] = *(const short8*)(As + (wm * 64 + mi * 16 + rA) * LDA + k0);
            for (int ni = 0; ni < 2; ++ni)
                bfr[ni] = *(const short8*)(Bs + (wn * 32 + ni * 16 + rA) * LDA + k0);
            for (int mi = 0; mi < 4; ++mi)
                for (int ni = 0; ni < 2; ++ni)
                    acc[mi][ni] = __builtin_amdgcn_mfma_f32_16x16x32_bf16(
                        a[mi], bfr[ni], acc[mi][ni], 0, 0, 0);
        }
        __syncthreads();
    }
    // bias + relu + pool: wave (wm,wn) owns pool window wm, cols wn*32+ni*16+rA
    for (int ni = 0; ni < 2; ++ni) {
        const int col = wn * 32 + ni * 16 + rA;
        const float bias = b2[n0 + col];
        float s = 0.f;
        for (int mi = 0; mi < 4; ++mi)
            for (int r = 0; r < 4; ++r) {
                float v = acc[mi][ni][r] + bias;
                s += v > 0.f ? v : 0.f;
            }
        s += __shfl_xor(s, 16);
        s += __shfl_xor(s, 32);
        if (q4 == 0) pool[wm * 128 + col] = s;
    }
    __syncthreads();
    if (tid < 256) {
        const int wrow = tid >> 7, col = tid & 127;
        const int p = (t0 >> 6) + wrow;
        y2[((size_t)(set * 32 + bb) * 4 + p) * 256 + n0 + col] = pool[tid] * (1.f / 64.f);
    }
}

// ---------------- VQ: coalesced float4 distance, argmin, assemble ----------------
__global__ __launch_bounds__(256) void vq_kernel(
    const float* __restrict__ y2, const float* __restrict__ cbiT, const float* __restrict__ cbvT,
    const float* __restrict__ cbi, const float* __restrict__ cbv,
    const float* __restrict__ pos, float* __restrict__ ztr, ushort* __restrict__ xbf,
    float* __restrict__ accum)
{
    const int q = blockIdx.x;
    const int tid = threadIdx.x;
    const int set = q >> 7, bb = (q >> 2) & 31, p = q & 3;
    __shared__ float zloc[256];
    __shared__ float bestv[4];
    __shared__ int   besti[4];
    __shared__ int   code_sh[2];
    __shared__ float wsum2[4];
    zloc[tid] = y2[(size_t)q * 256 + tid];
    __syncthreads();
    const int w = tid >> 6, lane = tid & 63;
    const int half = w >> 1, sub = w & 1;
    const float4* cbT4 = (const float4*)(half ? cbvT : cbiT);  // [d][128 float4]
    const float* zh = zloc + half * 128;
    const int k4 = sub * 64 + lane;              // float4 group: codes 4k4..4k4+3
    float a0 = 0.f, a1 = 0.f, a2 = 0.f, a3 = 0.f;
    for (int d = 0; d < 128; ++d) {
        float4 v = cbT4[d * 128 + k4];
        const float z = zh[d];
        float d0 = z - v.x, d1 = z - v.y, d2 = z - v.z, d3 = z - v.w;
        a0 += d0 * d0; a1 += d1 * d1; a2 += d2 * d2; a3 += d3 * d3;
    }
    float best = a0; int bidx = k4 * 4;
    if (a1 < best) { best = a1; bidx = k4 * 4 + 1; }
    if (a2 < best) { best = a2; bidx = k4 * 4 + 2; }
    if (a3 < best) { best = a3; bidx = k4 * 4 + 3; }
    for (int off = 32; off > 0; off >>= 1) {
        float ov = __shfl_xor(best, off);
        int   oi = __shfl_xor(bidx, off);
        if (ov < best || (ov == best && oi < bidx)) { best = ov; bidx = oi; }
    }
    if (lane == 0) { bestv[w] = best; besti[w] = bidx; }
    __syncthreads();
    if (tid < 2) {
        float v0 = bestv[tid * 2], v1 = bestv[tid * 2 + 1];
        int   i0 = besti[tid * 2], i1 = besti[tid * 2 + 1];
        code_sh[tid] = (v1 < v0 || (v1 == v0 && i1 < i0)) ? i1 : i0;
    }
    __syncthreads();
    const int hh = tid >> 7, d = tid & 127;
    const int code = code_sh[hh];
    const float* cb = hh ? cbv : cbi;
    const float zq = cb[code * 128 + d];
    const float diff = zloc[hh * 128 + d] - zq;
    float sq = diff * diff;
    for (int off = 32; off > 0; off >>= 1) sq += __shfl_xor(sq, off);
    if (lane == 0) wsum2[w] = sq;
    const int s = (set * 2 + hh) * 4 + p;
    const float val = zq + pos[s * 128 + d];
    ztr[((size_t)bb * 24 + s) * 128 + d] = val;
    xbf[((size_t)bb * 24 + s) * 128 + d] = f2bf(val);
    __syncthreads();
    if (tid == 0) atomicAdd(&accum[0], wsum2[0] + wsum2[1] + wsum2[2] + wsum2[3]);
}

// ---------------- generic 64x64-tile bf16 GEMM: C = A(MxK) . B(NxK)^T ----------------
template<int KTOT, int NTOT, int RELU, int OUTBF>
__global__ __launch_bounds__(256) void gemm64_kernel(
    const ushort* __restrict__ A, const ushort* __restrict__ Bw,
    const float* __restrict__ bias, void* __restrict__ Co)
{
    constexpr int NBLK = NTOT / 64;
    constexpr int LDA = 136;
    __shared__ ushort As[64 * LDA];
    __shared__ ushort Bs[64 * LDA];
    const int tid = threadIdx.x;
    const int mblk = blockIdx.x / NBLK, nblk = blockIdx.x % NBLK;
    const int m0 = mblk * 64, n0 = nblk * 64;
    const int w = tid >> 6, lane = tid & 63;
    const int rA = lane & 15, q4 = lane >> 4;
    const int ch = tid & 15, rowst = tid >> 4;

    floatx4 acc[4];
    for (int mi = 0; mi < 4; ++mi) acc[mi] = (floatx4)(0.f);

    for (int kc = 0; kc < KTOT / 128; ++kc) {
        for (int i = 0; i < 4; ++i) {
            const int row = i * 16 + rowst;
            *(uint4*)(As + row * LDA + ch * 8) =
                *(const uint4*)(A + (size_t)(m0 + row) * KTOT + kc * 128 + ch * 8);
            *(uint4*)(Bs + row * LDA + ch * 8) =
                *(const uint4*)(Bw + (size_t)(n0 + row) * KTOT + kc * 128 + ch * 8);
        }
        __syncthreads();
        for (int ks = 0; ks < 4; ++ks) {
            const int k0 = ks * 32 + q4 * 8;
            short8 bfr = *(const short8*)(Bs + (w * 16 + rA) * LDA + k0);
            for (int mi = 0; mi < 4; ++mi) {
                short8 a = *(const short8*)(As + (mi * 16 + rA) * LDA + k0);
                acc[mi] = __builtin_amdgcn_mfma_f32_16x16x32_bf16(a, bfr, acc[mi], 0, 0, 0);
            }
        }
        __syncthreads();
    }
    const int col = n0 + w * 16 + rA;
    const float bs = bias[col];
    for (int mi = 0; mi < 4; ++mi) {
        for (int r = 0; r < 4; ++r) {
            const int row = m0 + mi * 16 + q4 * 4 + r;
            float vv = acc[mi][r] + bs;
            if (RELU) vv = vv > 0.f ? vv : 0.f;
            if (OUTBF) ((ushort*)Co)[(size_t)row * NTOT + col] = f2bf(vv);
            else       ((float*)Co)[(size_t)row * NTOT + col]  = vv;
        }
    }
}

// ---------------- 64x128-tile GEMM + residual + LayerNorm epilogue ----------------
template<int KTOT, int WRITE_F32>
__global__ __launch_bounds__(256) void gemm_ln_kernel(
    const ushort* __restrict__ A, const ushort* __restrict__ Bw,
    const float* __restrict__ bias, const float* __restrict__ resid,
    const float* __restrict__ g, const float* __restrict__ beta,
    ushort* __restrict__ outbf, float* __restrict__ outf)
{
    constexpr int LDA = 136;
    __shared__ ushort As[64 * LDA];
    __shared__ ushort Bs[128 * LDA];
    __shared__ float ps[64 * 4], pq[64 * 4], muv[64], invv[64];
    const int tid = threadIdx.x;
    const int m0 = blockIdx.x * 64;
    const int w = tid >> 6, lane = tid & 63;
    const int rA = lane & 15, q4 = lane >> 4;
    const int ch = tid & 15, rowst = tid >> 4;

    floatx4 acc[4][2];
    for (int mi = 0; mi < 4; ++mi)
        for (int ni = 0; ni < 2; ++ni)
            acc[mi][ni] = (floatx4)(0.f);

    for (int kc = 0; kc < KTOT / 128; ++kc) {
        for (int i = 0; i < 4; ++i) {
            const int row = i * 16 + rowst;
            *(uint4*)(As + row * LDA + ch * 8) =
                *(const uint4*)(A + (size_t)(m0 + row) * KTOT + kc * 128 + ch * 8);
        }
        for (int i = 0; i < 8; ++i) {
            const int row = i * 16 + rowst;
            *(uint4*)(Bs + row * LDA + ch * 8) =
                *(const uint4*)(Bw + (size_t)row * KTOT + kc * 128 + ch * 8);
        }
        __syncthreads();
        for (int ks = 0; ks < 4; ++ks) {
            const int k0 = ks * 32 + q4 * 8;
            short8 a[4], bfr[2];
            for (int mi = 0; mi < 4; ++mi)
                a[mi] = *(const short8*)(As + (mi * 16 + rA) * LDA + k0);
            for (int ni = 0; ni < 2; ++ni)
                bfr[ni] = *(const short8*)(Bs + ((w * 2 + ni) * 16 + rA) * LDA + k0);
            for (int mi = 0; mi < 4; ++mi)
                for (int ni = 0; ni < 2; ++ni)
                    acc[mi][ni] = __builtin_amdgcn_mfma_f32_16x16x32_bf16(
                        a[mi], bfr[ni], acc[mi][ni], 0, 0, 0);
        }
        __syncthreads();
    }
    for (int ni = 0; ni < 2; ++ni) {
        const int col = (w * 2 + ni) * 16 + rA;
        const float bs = bias[col];
        for (int mi = 0; mi < 4; ++mi)
            for (int r = 0; r < 4; ++r) {
                const int row = m0 + mi * 16 + q4 * 4 + r;
                acc[mi][ni][r] += bs + resid[(size_t)row * 128 + col];
            }
    }
    for (int mi = 0; mi < 4; ++mi)
        for (int r = 0; r < 4; ++r) {
            float s  = acc[mi][0][r] + acc[mi][1][r];
            float sq = acc[mi][0][r] * acc[mi][0][r] + acc[mi][1][r] * acc[mi][1][r];
            for (int off = 1; off < 16; off <<= 1) {
                s  += __shfl_xor(s, off);
                sq += __shfl_xor(sq, off);
            }
            if (rA == 0) {
                const int rl = mi * 16 + q4 * 4 + r;
                ps[rl * 4 + w] = s;
                pq[rl * 4 + w] = sq;
            }
        }
    __syncthreads();
    if (tid < 64) {
        float s  = ps[tid * 4] + ps[tid * 4 + 1] + ps[tid * 4 + 2] + ps[tid * 4 + 3];
        float sq = pq[tid * 4] + pq[tid * 4 + 1] + pq[tid * 4 + 2] + pq[tid * 4 + 3];
        float mu = s * (1.f / 128.f);
        float var = sq * (1.f / 128.f) - mu * mu;
        muv[tid] = mu;
        invv[tid] = rsqrtf(var + 1e-5f);
    }
    __syncthreads();
    for (int ni = 0; ni < 2; ++ni) {
        const int col = (w * 2 + ni) * 16 + rA;
        const float gg = g[col], bb = beta[col];
        for (int mi = 0; mi < 4; ++mi)
            for (int r = 0; r < 4; ++r) {
                const int rl = mi * 16 + q4 * 4 + r;
                const int row = m0 + rl;
                float v = (acc[mi][ni][r] - muv[rl]) * invv[rl] * gg + bb;
                outbf[(size_t)row * 128 + col] = f2bf(v);
                if (WRITE_F32) outf[(size_t)row * 128 + col] = v;
            }
    }
}

// ---------------- attention: one block per (b, h) ----------------
__global__ __launch_bounds__(64) void attn_kernel(
    const float* __restrict__ qkvb, ushort* __restrict__ obuf)
{
    const int bh = blockIdx.x;
    const int b = bh >> 2, h = bh & 3;
    const int tid = threadIdx.x;
    __shared__ float q[24 * 32], k[24 * 32], v[24 * 32], sc[24 * 24];
    for (int i = 0; i < 12; ++i) {
        const int idx = i * 64 + tid;
        const int s = idx >> 5, d = idx & 31;
        const size_t base = ((size_t)(b * 24 + s)) * 384 + h * 32 + d;
        q[idx] = qkvb[base];
        k[idx] = qkvb[base + 128];
        v[idx] = qkvb[base + 256];
    }
    __syncthreads();
    for (int i = 0; i < 9; ++i) {
        const int e = i * 64 + tid;
        const int si = e / 24, j = e - si * 24;
        float a = 0.f;
        for (int d = 0; d < 32; ++d) a += q[si * 32 + d] * k[j * 32 + d];
        sc[si * 24 + j] = a * 0.17677669529663687f;
    }
    __syncthreads();
    if (tid < 24) {
        float* row = sc + tid * 24;
        float m = row[0];
        for (int j = 1; j < 24; ++j) m = row[j] > m ? row[j] : m;
        float ssum = 0.f;
        for (int j = 0; j < 24; ++j) { float e = __expf(row[j] - m); row[j] = e; ssum += e; }
        float inv = 1.f / ssum;
        for (int j = 0; j < 24; ++j) row[j] *= inv;
    }
    __syncthreads();
    for (int i = 0; i < 12; ++i) {
        const int idx = i * 64 + tid;
        const int s = idx >> 5, d = idx & 31;
        float a = 0.f;
        for (int j = 0; j < 24; ++j) a += sc[s * 24 + j] * v[j * 32 + d];
        obuf[((size_t)(b * 24 + s)) * 128 + h * 32 + d] = f2bf(a);
    }
}

// ---------------- lora_a: h[b][r] = lora_a[r] . z[b], grid 32 ----------------
__global__ __launch_bounds__(256) void lora_kernel(
    const ushort* __restrict__ zbf, const float* __restrict__ lora_a,
    float* __restrict__ hbuf)
{
    const int b = blockIdx.x;
    const int tid = threadIdx.x;
    const int w = tid >> 6, lane = tid & 63;
    __shared__ float zl[3072];
    for (int idx = tid; idx < 3072; idx += 256) zl[idx] = bf2f(zbf[(size_t)b * 3072 + idx]);
    __syncthreads();
    for (int rr = 0; rr < 2; ++rr) {
        const int r = w + rr * 4;
        float acc = 0.f;
        for (int idx = lane; idx < 3072; idx += 64)
            acc += lora_a[(size_t)r * 3072 + idx] * zl[idx];
        for (int off = 32; off > 0; off >>= 1) acc += __shfl_xor(acc, off);
        if (lane == 0) hbuf[b * 8 + r] = acc;
    }
}

// ---------------- logits + log-softmax + NLL + fused finalize ----------------
__global__ __launch_bounds__(256) void logits_kernel(
    const float* __restrict__ hbuf, const float* __restrict__ lora_b,
    const int* __restrict__ tokc, float* __restrict__ accum, float* __restrict__ out)
{
    const int tid = threadIdx.x;
    const int tcb = blockIdx.x;          // t*8 + c
    __shared__ float hl[256];
    __shared__ float wsum[4];
    __shared__ float ltok;
    hl[tid] = hbuf[tid];
    float wr[4][8];
    for (int i = 0; i < 4; ++i) {
        const float4* pw = (const float4*)(lora_b + ((size_t)tcb * 1024 + tid + 256 * i) * 8);
        float4 x = pw[0], y = pw[1];
        wr[i][0] = x.x; wr[i][1] = x.y; wr[i][2] = x.z; wr[i][3] = x.w;
        wr[i][4] = y.x; wr[i][5] = y.y; wr[i][6] = y.z; wr[i][7] = y.w;
    }
    __syncthreads();
    float nll = 0.f;
    for (int bb = 0; bb < 32; ++bb) {
        const int tv = tokc[bb * 2048 + tcb];
        const float* h = hl + bb * 8;
        float h0 = h[0], h1 = h[1], h2 = h[2], h3 = h[3];
        float h4 = h[4], h5 = h[5], h6 = h[6], h7 = h[7];
        float sl = 0.f;
        for (int i = 0; i < 4; ++i) {
            float lg = h0 * wr[i][0] + h1 * wr[i][1] + h2 * wr[i][2] + h3 * wr[i][3]
                     + h4 * wr[i][4] + h5 * wr[i][5] + h6 * wr[i][6] + h7 * wr[i][7];
            sl += __expf(lg);
            if (tid + 256 * i == tv) ltok = lg;
        }
        for (int off = 32; off > 0; off >>= 1) sl += __shfl_xor(sl, off);
        if ((tid & 63) == 0) wsum[tid >> 6] = sl;
        __syncthreads();
        if (tid == 0) nll += logf(wsum[0] + wsum[1] + wsum[2] + wsum[3]) - ltok;
        __syncthreads();
    }
    if (tid == 0) {
        atomicAdd(&accum[1], nll);
        __threadfence();
        unsigned int prev = atomicAdd((unsigned int*)(accum + 2), 1u);
        if (prev == 2047u) {
            float vq  = atomicAdd(&accum[0], 0.f);
            float rec = atomicAdd(&accum[1], 0.f);
            out[0] = rec * (1.f / 65536.f) + 0.05f * vq * (1.f / 16384.f);
        }
    }
}

// ---------------- host ----------------
extern "C" void kernel_launch(void* const* d_in, const int* in_sizes, int n_in,
                              void* d_out, int out_size, void* d_ws, size_t ws_size,
                              hipStream_t stream) {
    const int*   tp   = (const int*)d_in[0];
    const int*   tcu  = (const int*)d_in[1];
    const int*   tn   = (const int*)d_in[2];
    const float* emb  = (const float*)d_in[3];
    const float* w1   = (const float*)d_in[4];
    const float* b1   = (const float*)d_in[5];
    const float* w2   = (const float*)d_in[6];
    const float* b2   = (const float*)d_in[7];
    const float* cbi  = (const float*)d_in[8];
    const float* cbv  = (const float*)d_in[9];
    const float* pos  = (const float*)d_in[10];
    const float* aiw  = (const float*)d_in[11];
    const float* aib  = (const float*)d_in[12];
    const float* aow  = (const float*)d_in[13];
    const float* aob  = (const float*)d_in[14];
    const float* g1   = (const float*)d_in[15];
    const float* be1  = (const float*)d_in[16];
    const float* l1w  = (const float*)d_in[17];
    const float* l1b  = (const float*)d_in[18];
    const float* l2w  = (const float*)d_in[19];
    const float* l2b  = (const float*)d_in[20];
    const float* g2   = (const float*)d_in[21];
    const float* be2  = (const float*)d_in[22];
    const float* lra  = (const float*)d_in[23];
    const float* lrb  = (const float*)d_in[24];

    char* wsb = (char*)d_ws;
    ushort* ebf  = (ushort*)(wsb + 0);            // 262144 B
    ushort* w1bf = (ushort*)(wsb + 262144);       // 3145728 B
    ushort* w2bf = (ushort*)(wsb + 3407872);      // 262144 B
    float*  cbiT = (float*)(wsb + 3670016);       // 262144 B
    float*  cbvT = (float*)(wsb + 3932160);       // 262144 B
    ushort* y1   = (ushort*)(wsb + 4194304);      // 25165824 B (dead after conv2)
    float*  y2   = (float*)(wsb + 29360128);      // 393216 B
    float*  ztr  = (float*)(wsb + 29753344);      // 393216 B
    float*  hbuf = (float*)(wsb + 30146560);      // 1024 B
    float*  accum= (float*)(wsb + 30147584);      // 64 B
    ushort* aiwbf= (ushort*)(wsb + 30147648);     // 98304 B
    ushort* aowbf= (ushort*)(wsb + 30245952);     // 32768 B
    ushort* l1wbf= (ushort*)(wsb + 30278720);     // 131072 B
    ushort* l2wbf= (ushort*)(wsb + 30409792);     // 131072 B -> 30540864
    if (ws_size < 30540864) return;

    // transformer temporaries alias the (dead-by-then) y1 region
    float*  qkvb = (float*)(wsb + 4194304);       // 1179648 B
    ushort* obuf = (ushort*)(wsb + 5373952);      // 196608 B
    ushort* x1bf = (ushort*)(wsb + 5570560);      // 196608 B
    float*  x1f  = (float*)(wsb + 5767168);       // 393216 B
    ushort* hff  = (ushort*)(wsb + 6160384);      // 786432 B
    ushort* zbf  = (ushort*)(wsb + 6946816);      // 196608 B
    ushort* xbf  = (ushort*)(wsb + 7143424);      // 196608 B

    prep_all<<<8512, 256, 0, stream>>>(emb, w1, w2, cbi, cbv, aiw, aow, l1w, l2w,
                                       ebf, w1bf, w2bf, cbiT, cbvT,
                                       aiwbf, aowbf, l1wbf, l2wbf, accum);
    conv1_mfma<<<768, 512, 0, stream>>>(tp, tcu, tn, ebf, w1bf, b1, y1);
    conv2_mfma<<<384, 512, 0, stream>>>(y1, w2bf, b2, y2);
    vq_kernel<<<384, 256, 0, stream>>>(y2, cbiT, cbvT, cbi, cbv, pos, ztr, xbf, accum);
    gemm64_kernel<128, 384, 0, 0><<<72, 256, 0, stream>>>(xbf, aiwbf, aib, qkvb);
    attn_kernel<<<128, 64, 0, stream>>>(qkvb, obuf);
    gemm_ln_kernel<128, 1><<<12, 256, 0, stream>>>(obuf, aowbf, aob, ztr, g1, be1, x1bf, x1f);
    gemm64_kernel<128, 512, 1, 1><<<96, 256, 0, stream>>>(x1bf, l1wbf, l1b, hff);
    gemm_ln_kernel<512, 0><<<12, 256, 0, stream>>>(hff, l2wbf, l2b, x1f, g2, be2, zbf, nullptr);
    lora_kernel<<<32, 256, 0, stream>>>(zbf, lra, hbuf);
    logits_kernel<<<2048, 256, 0, stream>>>(hbuf, lrb, tcu, accum, (float*)d_out);
}